// Round 6
// baseline (390.193 us; speedup 1.0000x reference)
//
#include <hip/hip_runtime.h>
#include <hip/hip_cooperative_groups.h>

namespace cg = cooperative_groups;

// SpecNCutout: out = select(mask, mean(x), x)
// x: (B=128, H=256, W=1024, C=1) fp32. mask = union of 5 clipped rects/batch.
//
// R5: traffic is exhausted (R0->R4 removed ~130MB, dur unchanged -> the
// controllable cost is dispatch gaps, not bytes). Fuse both passes into one
// cooperative kernel with a grid.sync() between copy+reduce and hole-fill.
//  - 1024 blocks x 256 thr, __launch_bounds__(256,4) -> exactly 1024
//    co-resident (4 blocks/CU), comfortably under the 128-VGPR cap.
//  - Phase A reproduces R4's 2048 partials in the IDENTICAL summation order
//    (each block = two 16-row groups), phase B reduces them with R4's exact
//    tree -> mean is bit-identical -> output bit-identical (absmax 0.0).
//  - If hipLaunchCooperativeKernel errors (capture/occupancy), fall back to
//    the verbatim R4 two-kernel path: this round cannot regress.

#define BB 128
#define HH 256
#define WW 1024
#define N_HOLES 5
#define HOLE_MINW (WW / 10)   // 102
#define HOLE_MINH (HH / 10)   // 25
#define N_ELEM (BB * HH * WW) // 33554432
#define ROWS_PER_BLOCK 16
#define RED_BLOCKS (BB * HH / ROWS_PER_BLOCK)  // 2048
#define ROW_SLICES 8
#define FBLOCKS 1024
#define FROWS 32              // rows per fused block = 2 x 16-row groups
#define FILL_UNITS (BB * N_HOLES * ROW_SLICES) // 5120

// ---------------- fused cooperative kernel ----------------
__global__ __launch_bounds__(256, 4) void fused_kernel(
    const float* __restrict__ x, float* __restrict__ out,
    const int* __restrict__ xs, const int* __restrict__ ys,
    const int* __restrict__ xs_w_raw, const int* __restrict__ ys_h_raw,
    const float* __restrict__ act_rand,
    float* __restrict__ partials) {
  int blk = blockIdx.x;
  int b = blk >> 3;                 // 8 blocks per batch (256 rows / 32)
  int row0 = blk * FROWS;
  int tid = threadIdx.x;
  int lane = tid & 63;
  int wave = tid >> 6;
  __shared__ float wsum[4];
  __shared__ float mean_sh;

  // Per-block (batch-uniform) hole rects.
  int ys_s[N_HOLES], ys_e[N_HOLES], xlo[N_HOLES], xhi[N_HOLES];
  #pragma unroll
  for (int n = 0; n < N_HOLES; ++n) {
    int base = b * N_HOLES + n;
    int cx = xs[base];
    int cy = ys[base];
    int hw = (xs_w_raw[base] + HOLE_MINW) >> 1;  // xs_w // 2
    int hh = (ys_h_raw[base] + HOLE_MINH) >> 1;  // ys_h // 2
    bool act = act_rand[base] < 1.0f;            // PROB = 1.0
    int yss = min(max(cy - hh, 0), HH - 2);
    int yse = min(max(cy + hh, 1), HH - 1);
    ys_s[n] = act ? yss : 1;
    ys_e[n] = act ? yse : 0;                     // empty if inactive
    xlo[n] = min(max(cx - hw, 0), WW - 2);
    xhi[n] = min(max(cx + hw, 1), WW - 1);
  }

  const float4* x4 = (const float4*)x;
  float4* out4 = (float4*)out;
  int w0 = tid * 4;                 // W=1024 = 256 threads * 4

  // Phase A: copy 32 rows (skip fully-hole float4s), two 16-row partial
  // groups with R4-identical per-thread accumulation order.
  #pragma unroll
  for (int g = 0; g < 2; ++g) {
    float s = 0.0f;
    for (int rr = 0; rr < ROWS_PER_BLOCK; ++rr) {
      int row = row0 + g * ROWS_PER_BLOCK + rr;
      int h = row & (HH - 1);
      long i = (long)row * (WW / 4) + tid;
      float4 v = x4[i];
      s += (v.x + v.y) + (v.z + v.w);

      bool all_hole = true;
      #pragma unroll
      for (int j = 0; j < 4; ++j) {
        int w = w0 + j;
        bool m = false;
        #pragma unroll
        for (int n = 0; n < N_HOLES; ++n) {
          bool in_row = (ys_s[n] <= h) && (h <= ys_e[n]);
          m = m || (in_row && (xlo[n] <= w) && (w <= xhi[n]));
        }
        all_hole = all_hole && m;
      }
      if (!all_hole) out4[i] = v;
    }
    #pragma unroll
    for (int off = 32; off > 0; off >>= 1) s += __shfl_down(s, off, 64);
    if (lane == 0) wsum[wave] = s;
    __syncthreads();
    if (tid == 0)
      partials[2 * blk + g] = (wsum[0] + wsum[1]) + (wsum[2] + wsum[3]);
    __syncthreads();
  }

  // All partials complete + visible after grid sync.
  cg::this_grid().sync();

  // Phase B: mean via R4's exact reduction tree over 2048 partials.
  {
    float s = 0.0f;
    for (int i = tid; i < RED_BLOCKS; i += 256) s += partials[i];
    #pragma unroll
    for (int off = 32; off > 0; off >>= 1) s += __shfl_down(s, off, 64);
    if (lane == 0) wsum[wave] = s;
    __syncthreads();
    if (tid == 0) {
      float t = (wsum[0] + wsum[1]) + (wsum[2] + wsum[3]);
      mean_sh = t * (1.0f / (float)N_ELEM);
    }
    __syncthreads();
  }
  float mean = mean_sh;

  // Fill hole spans: 5120 (batch, hole, slice) units over 1024 blocks.
  for (int u = blk; u < FILL_UNITS; u += FBLOCKS) {
    int b2 = u / (N_HOLES * ROW_SLICES);
    int rem = u % (N_HOLES * ROW_SLICES);
    int n = rem / ROW_SLICES;
    int slice = rem % ROW_SLICES;

    int base = b2 * N_HOLES + n;
    if (!(act_rand[base] < 1.0f)) continue;      // PROB = 1.0, always true
    int cx = xs[base];
    int cy = ys[base];
    int hw = (xs_w_raw[base] + HOLE_MINW) >> 1;
    int hh = (ys_h_raw[base] + HOLE_MINH) >> 1;
    int yss = min(max(cy - hh, 0), HH - 2);
    int yse = min(max(cy + hh, 1), HH - 1);
    int xss = min(max(cx - hw, 0), WW - 2);
    int xse = min(max(cx + hw, 1), WW - 1);

    // Overlapping holes double-write the same bit pattern: race-free.
    for (int h = yss + slice; h <= yse; h += ROW_SLICES) {
      long rowbase = (long)(b2 * HH + h) * WW;
      for (int w = xss + tid; w <= xse; w += 256) {
        out[rowbase + w] = mean;
      }
    }
  }
}

// ---------------- fallback: verbatim R4 two-kernel path ----------------
__global__ __launch_bounds__(256) void copy_reduce_kernel(
    const float* __restrict__ x, float* __restrict__ out,
    const int* __restrict__ xs, const int* __restrict__ ys,
    const int* __restrict__ xs_w_raw, const int* __restrict__ ys_h_raw,
    const float* __restrict__ act_rand,
    float* __restrict__ partials) {
  int blk = blockIdx.x;
  int b = blk >> 4;
  int row0 = blk * ROWS_PER_BLOCK;

  int ys_s[N_HOLES], ys_e[N_HOLES], xlo[N_HOLES], xhi[N_HOLES];
  #pragma unroll
  for (int n = 0; n < N_HOLES; ++n) {
    int base = b * N_HOLES + n;
    int cx = xs[base];
    int cy = ys[base];
    int hw = (xs_w_raw[base] + HOLE_MINW) >> 1;
    int hh = (ys_h_raw[base] + HOLE_MINH) >> 1;
    bool act = act_rand[base] < 1.0f;
    int yss = min(max(cy - hh, 0), HH - 2);
    int yse = min(max(cy + hh, 1), HH - 1);
    ys_s[n] = act ? yss : 1;
    ys_e[n] = act ? yse : 0;
    xlo[n] = min(max(cx - hw, 0), WW - 2);
    xhi[n] = min(max(cx + hw, 1), WW - 1);
  }

  const float4* x4 = (const float4*)x;
  float4* out4 = (float4*)out;
  int tid = threadIdx.x;
  int w0 = tid * 4;

  float s = 0.0f;
  for (int rr = 0; rr < ROWS_PER_BLOCK; ++rr) {
    int row = row0 + rr;
    int h = row & (HH - 1);
    long i = (long)row * (WW / 4) + tid;
    float4 v = x4[i];
    s += (v.x + v.y) + (v.z + v.w);

    bool all_hole = true;
    #pragma unroll
    for (int j = 0; j < 4; ++j) {
      int w = w0 + j;
      bool m = false;
      #pragma unroll
      for (int n = 0; n < N_HOLES; ++n) {
        bool in_row = (ys_s[n] <= h) && (h <= ys_e[n]);
        m = m || (in_row && (xlo[n] <= w) && (w <= xhi[n]));
      }
      all_hole = all_hole && m;
    }
    if (!all_hole) out4[i] = v;
  }

  #pragma unroll
  for (int off = 32; off > 0; off >>= 1) s += __shfl_down(s, off, 64);
  __shared__ float wsum[4];
  int lane = threadIdx.x & 63;
  int wave = threadIdx.x >> 6;
  if (lane == 0) wsum[wave] = s;
  __syncthreads();
  if (threadIdx.x == 0)
    partials[blockIdx.x] = (wsum[0] + wsum[1]) + (wsum[2] + wsum[3]);
}

__global__ __launch_bounds__(256) void fill_holes_kernel(
    const int* __restrict__ xs, const int* __restrict__ ys,
    const int* __restrict__ xs_w_raw, const int* __restrict__ ys_h_raw,
    const float* __restrict__ act_rand,
    const float* __restrict__ partials,
    float* __restrict__ out) {
  float s = 0.0f;
  for (int i = threadIdx.x; i < RED_BLOCKS; i += 256) s += partials[i];
  #pragma unroll
  for (int off = 32; off > 0; off >>= 1) s += __shfl_down(s, off, 64);
  __shared__ float wsum[4];
  __shared__ float mean_sh;
  int lane = threadIdx.x & 63;
  int wave = threadIdx.x >> 6;
  if (lane == 0) wsum[wave] = s;
  __syncthreads();
  if (threadIdx.x == 0) {
    float t = (wsum[0] + wsum[1]) + (wsum[2] + wsum[3]);
    mean_sh = t * (1.0f / (float)N_ELEM);
  }
  __syncthreads();
  float mean = mean_sh;

  int bid = blockIdx.x;
  int b = bid / (N_HOLES * ROW_SLICES);
  int rem = bid % (N_HOLES * ROW_SLICES);
  int n = rem / ROW_SLICES;
  int slice = rem % ROW_SLICES;

  int base = b * N_HOLES + n;
  if (!(act_rand[base] < 1.0f)) return;
  int cx = xs[base];
  int cy = ys[base];
  int hw = (xs_w_raw[base] + HOLE_MINW) >> 1;
  int hh = (ys_h_raw[base] + HOLE_MINH) >> 1;
  int ys_s = min(max(cy - hh, 0), HH - 2);
  int ys_e = min(max(cy + hh, 1), HH - 1);
  int xs_s = min(max(cx - hw, 0), WW - 2);
  int xs_e = min(max(cx + hw, 1), WW - 1);

  for (int h = ys_s + slice; h <= ys_e; h += ROW_SLICES) {
    long rowbase = (long)(b * HH + h) * WW;
    for (int w = xs_s + (int)threadIdx.x; w <= xs_e; w += 256) {
      out[rowbase + w] = mean;
    }
  }
}

extern "C" void kernel_launch(void* const* d_in, const int* in_sizes, int n_in,
                              void* d_out, int out_size, void* d_ws, size_t ws_size,
                              hipStream_t stream) {
  const float* x        = (const float*)d_in[0];
  const int* xs         = (const int*)d_in[1];
  const int* ys         = (const int*)d_in[2];
  const int* xs_w_raw   = (const int*)d_in[3];
  const int* ys_h_raw   = (const int*)d_in[4];
  const float* act_rand = (const float*)d_in[5];
  float* out = (float*)d_out;

  float* partials = (float*)d_ws;                // RED_BLOCKS floats

  void* args[] = {(void*)&x, (void*)&out, (void*)&xs, (void*)&ys,
                  (void*)&xs_w_raw, (void*)&ys_h_raw, (void*)&act_rand,
                  (void*)&partials};
  hipError_t err = hipLaunchCooperativeKernel(
      (const void*)fused_kernel, dim3(FBLOCKS), dim3(256), args, 0, stream);
  if (err != hipSuccess) {
    // Fallback: R4 two-kernel path (bit-identical output).
    copy_reduce_kernel<<<RED_BLOCKS, 256, 0, stream>>>(
        x, out, xs, ys, xs_w_raw, ys_h_raw, act_rand, partials);
    fill_holes_kernel<<<BB * N_HOLES * ROW_SLICES, 256, 0, stream>>>(
        xs, ys, xs_w_raw, ys_h_raw, act_rand, partials, out);
  }
}

// Round 7
// 268.959 us; speedup vs baseline: 1.4508x; 1.4508x over previous
//
#include <hip/hip_runtime.h>

// SpecNCutout: out = select(mask, mean(x), x)
// x: (B=128, H=256, W=1024, C=1) fp32. mask = union of 5 clipped rects/batch.
//
// R7: MLP fix. R6's cooperative-fusion post-mortem showed VGPR_Count=20 ->
// only ~2-3 loads in flight per wave -> ~2-4 TB/s latency-bound copy
// (in-flight bytes / 900cy HBM latency), NOT bandwidth-bound. This round:
//  - back to the R4 two-kernel structure (fusion regressed: grid.sync +
//    halved co-residency),
//  - pass 1 explicitly batches 8 independent float4 loads into registers
//    per chunk (2 chunks x 8 rows = 16 rows/block, same order as R4 ->
//    bit-identical partials/mean/output),
//  - hole-coverage test hoisted: covers_w[n] is block/thread-invariant,
//    per-row test is 5x ~3 ops. all_hole is an under-approximation (single
//    hole must cover the float4) — always safe, since pass 2 overwrites
//    every hole pixel regardless.
// Target: copy pass ~40us @ ~6 TB/s; total kernel time ~50us.

#define BB 128
#define HH 256
#define WW 1024
#define N_HOLES 5
#define HOLE_MINW (WW / 10)   // 102
#define HOLE_MINH (HH / 10)   // 25
#define N_ELEM (BB * HH * WW) // 33554432
#define ROWS_PER_BLOCK 16
#define RED_BLOCKS (BB * HH / ROWS_PER_BLOCK)  // 2048
#define ROW_SLICES 8
#define BATCH_ROWS 8          // independent loads in flight per wave

// Pass 1: copy x->out (skipping float4s fully covered by a single hole)
// while accumulating the sum. Block blk = rows [blk*16, blk*16+16).
__global__ __launch_bounds__(256) void copy_reduce_kernel(
    const float* __restrict__ x, float* __restrict__ out,
    const int* __restrict__ xs, const int* __restrict__ ys,
    const int* __restrict__ xs_w_raw, const int* __restrict__ ys_h_raw,
    const float* __restrict__ act_rand,
    float* __restrict__ partials) {
  int blk = blockIdx.x;
  int b = blk >> 4;                 // 16 blocks per batch
  int row0 = blk * ROWS_PER_BLOCK;  // global row = b*HH + h
  int tid = threadIdx.x;
  int w0 = tid * 4;                 // W=1024 = 256 threads * 4

  // Per-block hole rects; covers_w[n] = hole n spans this thread's float4.
  int ys_s[N_HOLES], ys_e[N_HOLES];
  bool covers_w[N_HOLES];
  #pragma unroll
  for (int n = 0; n < N_HOLES; ++n) {
    int base = b * N_HOLES + n;
    int cx = xs[base];
    int cy = ys[base];
    int hw = (xs_w_raw[base] + HOLE_MINW) >> 1;  // xs_w // 2
    int hh = (ys_h_raw[base] + HOLE_MINH) >> 1;  // ys_h // 2
    bool act = act_rand[base] < 1.0f;            // PROB = 1.0
    int yss = min(max(cy - hh, 0), HH - 2);
    int yse = min(max(cy + hh, 1), HH - 1);
    ys_s[n] = act ? yss : 1;
    ys_e[n] = act ? yse : 0;                     // empty if inactive
    int xlo = min(max(cx - hw, 0), WW - 2);
    int xhi = min(max(cx + hw, 1), WW - 1);
    covers_w[n] = (xlo <= w0) && (w0 + 3 <= xhi);
  }

  const float4* x4 = (const float4*)x;
  float4* out4 = (float4*)out;

  float s = 0.0f;
  #pragma unroll
  for (int g = 0; g < ROWS_PER_BLOCK / BATCH_ROWS; ++g) {   // 2 chunks
    float4 v[BATCH_ROWS];
    // 8 independent loads issued back-to-back: ~4KB in flight per CU at
    // 32 waves/CU -> latency-covered, BW-bound.
    #pragma unroll
    for (int r = 0; r < BATCH_ROWS; ++r) {
      long i = (long)(row0 + g * BATCH_ROWS + r) * (WW / 4) + tid;
      v[r] = x4[i];
    }
    #pragma unroll
    for (int r = 0; r < BATCH_ROWS; ++r) {
      int row = row0 + g * BATCH_ROWS + r;
      int h = row & (HH - 1);
      // Same per-thread accumulation order as R4 (rows ascending).
      s += (v[r].x + v[r].y) + (v[r].z + v[r].w);
      bool all_hole = false;
      #pragma unroll
      for (int n = 0; n < N_HOLES; ++n)
        all_hole = all_hole ||
                   (covers_w[n] && (ys_s[n] <= h) && (h <= ys_e[n]));
      if (!all_hole) {
        long i = (long)row * (WW / 4) + tid;
        out4[i] = v[r];
      }
    }
  }

  #pragma unroll
  for (int off = 32; off > 0; off >>= 1) s += __shfl_down(s, off, 64);
  __shared__ float wsum[4];
  int lane = tid & 63;
  int wave = tid >> 6;
  if (lane == 0) wsum[wave] = s;
  __syncthreads();
  if (tid == 0)
    partials[blockIdx.x] = (wsum[0] + wsum[1]) + (wsum[2] + wsum[3]);
}

// Pass 2 (verbatim R4): write mean into hole spans. One block per
// (batch, hole, row-slice). Each block privately reduces the 2048 partials
// (8 KiB, L2-broadcast) with the identical tree -> bit-identical mean.
__global__ __launch_bounds__(256) void fill_holes_kernel(
    const int* __restrict__ xs, const int* __restrict__ ys,
    const int* __restrict__ xs_w_raw, const int* __restrict__ ys_h_raw,
    const float* __restrict__ act_rand,
    const float* __restrict__ partials,
    float* __restrict__ out) {
  float s = 0.0f;
  for (int i = threadIdx.x; i < RED_BLOCKS; i += 256) s += partials[i];
  #pragma unroll
  for (int off = 32; off > 0; off >>= 1) s += __shfl_down(s, off, 64);
  __shared__ float wsum[4];
  __shared__ float mean_sh;
  int lane = threadIdx.x & 63;
  int wave = threadIdx.x >> 6;
  if (lane == 0) wsum[wave] = s;
  __syncthreads();
  if (threadIdx.x == 0) {
    float t = (wsum[0] + wsum[1]) + (wsum[2] + wsum[3]);
    mean_sh = t * (1.0f / (float)N_ELEM);
  }
  __syncthreads();
  float mean = mean_sh;

  int bid = blockIdx.x;
  int b = bid / (N_HOLES * ROW_SLICES);
  int rem = bid % (N_HOLES * ROW_SLICES);
  int n = rem / ROW_SLICES;
  int slice = rem % ROW_SLICES;

  int base = b * N_HOLES + n;
  if (!(act_rand[base] < 1.0f)) return;          // PROB = 1.0, always true
  int cx = xs[base];
  int cy = ys[base];
  int hw = (xs_w_raw[base] + HOLE_MINW) >> 1;
  int hh = (ys_h_raw[base] + HOLE_MINH) >> 1;
  int ys_s = min(max(cy - hh, 0), HH - 2);
  int ys_e = min(max(cy + hh, 1), HH - 1);
  int xs_s = min(max(cx - hw, 0), WW - 2);
  int xs_e = min(max(cx + hw, 1), WW - 1);

  // Overlapping holes double-write the same bit pattern: race-free.
  for (int h = ys_s + slice; h <= ys_e; h += ROW_SLICES) {
    long rowbase = (long)(b * HH + h) * WW;
    for (int w = xs_s + (int)threadIdx.x; w <= xs_e; w += 256) {
      out[rowbase + w] = mean;
    }
  }
}

extern "C" void kernel_launch(void* const* d_in, const int* in_sizes, int n_in,
                              void* d_out, int out_size, void* d_ws, size_t ws_size,
                              hipStream_t stream) {
  const float* x        = (const float*)d_in[0];
  const int* xs         = (const int*)d_in[1];
  const int* ys         = (const int*)d_in[2];
  const int* xs_w_raw   = (const int*)d_in[3];
  const int* ys_h_raw   = (const int*)d_in[4];
  const float* act_rand = (const float*)d_in[5];
  float* out = (float*)d_out;

  float* partials = (float*)d_ws;                // RED_BLOCKS floats

  copy_reduce_kernel<<<RED_BLOCKS, 256, 0, stream>>>(
      x, out, xs, ys, xs_w_raw, ys_h_raw, act_rand, partials);
  fill_holes_kernel<<<BB * N_HOLES * ROW_SLICES, 256, 0, stream>>>(
      xs, ys, xs_w_raw, ys_h_raw, act_rand, partials, out);
}

// Round 8
// 266.157 us; speedup vs baseline: 1.4660x; 1.0105x over previous
//
#include <hip/hip_runtime.h>

// SpecNCutout: out = select(mask, mean(x), x)
// x: (B=128, H=256, W=1024, C=1) fp32. mask = union of 5 clipped rects/batch.
//
// R8: single-variable experiment vs R7 — UNCONDITIONAL stores in pass 1.
// Evidence: R1 (no skip) ran 3.4 TB/s; R4/R7 (skip-store) run 2.7 TB/s and
// no faster in absolute time despite 34 MB less write traffic. Theory G:
// partially-masked global_store_dwordx4 over hole boundaries creates
// partially-dirty L2 lines -> RMW on eviction + broken full-line write
// stream. Removing the skip restores pure streaming writes.
// Loads, batching, and summation order are byte-identical to R7 ->
// partials/mean bit-identical. Hole pixels get x here, then mean in pass 2
// -> final output bytes identical.

#define BB 128
#define HH 256
#define WW 1024
#define N_HOLES 5
#define HOLE_MINW (WW / 10)   // 102
#define HOLE_MINH (HH / 10)   // 25
#define N_ELEM (BB * HH * WW) // 33554432
#define ROWS_PER_BLOCK 16
#define RED_BLOCKS (BB * HH / ROWS_PER_BLOCK)  // 2048
#define ROW_SLICES 8
#define BATCH_ROWS 8          // independent loads in flight per wave

// Pass 1: copy x->out (unconditional) while accumulating the sum.
// Block blk = rows [blk*16, blk*16+16).
__global__ __launch_bounds__(256) void copy_reduce_kernel(
    const float* __restrict__ x, float* __restrict__ out,
    float* __restrict__ partials) {
  int blk = blockIdx.x;
  int row0 = blk * ROWS_PER_BLOCK;  // global row = b*HH + h
  int tid = threadIdx.x;

  const float4* x4 = (const float4*)x;
  float4* out4 = (float4*)out;

  float s = 0.0f;
  #pragma unroll
  for (int g = 0; g < ROWS_PER_BLOCK / BATCH_ROWS; ++g) {   // 2 chunks
    float4 v[BATCH_ROWS];
    #pragma unroll
    for (int r = 0; r < BATCH_ROWS; ++r) {
      long i = (long)(row0 + g * BATCH_ROWS + r) * (WW / 4) + tid;
      v[r] = x4[i];
    }
    #pragma unroll
    for (int r = 0; r < BATCH_ROWS; ++r) {
      // Same per-thread accumulation order as R7 (rows ascending).
      s += (v[r].x + v[r].y) + (v[r].z + v[r].w);
      long i = (long)(row0 + g * BATCH_ROWS + r) * (WW / 4) + tid;
      out4[i] = v[r];
    }
  }

  #pragma unroll
  for (int off = 32; off > 0; off >>= 1) s += __shfl_down(s, off, 64);
  __shared__ float wsum[4];
  int lane = tid & 63;
  int wave = tid >> 6;
  if (lane == 0) wsum[wave] = s;
  __syncthreads();
  if (tid == 0)
    partials[blockIdx.x] = (wsum[0] + wsum[1]) + (wsum[2] + wsum[3]);
}

// Pass 2 (verbatim R4): write mean into hole spans. One block per
// (batch, hole, row-slice). Each block privately reduces the 2048 partials
// (8 KiB, L2-broadcast) with the identical tree -> bit-identical mean.
__global__ __launch_bounds__(256) void fill_holes_kernel(
    const int* __restrict__ xs, const int* __restrict__ ys,
    const int* __restrict__ xs_w_raw, const int* __restrict__ ys_h_raw,
    const float* __restrict__ act_rand,
    const float* __restrict__ partials,
    float* __restrict__ out) {
  float s = 0.0f;
  for (int i = threadIdx.x; i < RED_BLOCKS; i += 256) s += partials[i];
  #pragma unroll
  for (int off = 32; off > 0; off >>= 1) s += __shfl_down(s, off, 64);
  __shared__ float wsum[4];
  __shared__ float mean_sh;
  int lane = threadIdx.x & 63;
  int wave = threadIdx.x >> 6;
  if (lane == 0) wsum[wave] = s;
  __syncthreads();
  if (threadIdx.x == 0) {
    float t = (wsum[0] + wsum[1]) + (wsum[2] + wsum[3]);
    mean_sh = t * (1.0f / (float)N_ELEM);
  }
  __syncthreads();
  float mean = mean_sh;

  int bid = blockIdx.x;
  int b = bid / (N_HOLES * ROW_SLICES);
  int rem = bid % (N_HOLES * ROW_SLICES);
  int n = rem / ROW_SLICES;
  int slice = rem % ROW_SLICES;

  int base = b * N_HOLES + n;
  if (!(act_rand[base] < 1.0f)) return;          // PROB = 1.0, always true
  int cx = xs[base];
  int cy = ys[base];
  int hw = (xs_w_raw[base] + HOLE_MINW) >> 1;
  int hh = (ys_h_raw[base] + HOLE_MINH) >> 1;
  int ys_s = min(max(cy - hh, 0), HH - 2);
  int ys_e = min(max(cy + hh, 1), HH - 1);
  int xs_s = min(max(cx - hw, 0), WW - 2);
  int xs_e = min(max(cx + hw, 1), WW - 1);

  // Overlapping holes double-write the same bit pattern: race-free.
  for (int h = ys_s + slice; h <= ys_e; h += ROW_SLICES) {
    long rowbase = (long)(b * HH + h) * WW;
    for (int w = xs_s + (int)threadIdx.x; w <= xs_e; w += 256) {
      out[rowbase + w] = mean;
    }
  }
}

extern "C" void kernel_launch(void* const* d_in, const int* in_sizes, int n_in,
                              void* d_out, int out_size, void* d_ws, size_t ws_size,
                              hipStream_t stream) {
  const float* x        = (const float*)d_in[0];
  const int* xs         = (const int*)d_in[1];
  const int* ys         = (const int*)d_in[2];
  const int* xs_w_raw   = (const int*)d_in[3];
  const int* ys_h_raw   = (const int*)d_in[4];
  const float* act_rand = (const float*)d_in[5];
  float* out = (float*)d_out;

  float* partials = (float*)d_ws;                // RED_BLOCKS floats

  copy_reduce_kernel<<<RED_BLOCKS, 256, 0, stream>>>(x, out, partials);
  fill_holes_kernel<<<BB * N_HOLES * ROW_SLICES, 256, 0, stream>>>(
      xs, ys, xs_w_raw, ys_h_raw, act_rand, partials, out);
}